// Round 16
// baseline (81.529 us; speedup 1.0000x reference)
//
#include <hip/hip_runtime.h>
#include <hip/hip_bf16.h>

#define S_ 2048
#define E_ 1024

typedef __attribute__((ext_vector_type(8))) short short8;
typedef __attribute__((ext_vector_type(4))) float f32x4;

__device__ __forceinline__ short f2bf(float f) {
    __hip_bfloat16 h = __float2bfloat16(f);
    return *(short*)&h;
}

__device__ __forceinline__ void g2l16(const void* g, void* l) {
    __builtin_amdgcn_global_load_lds(
        (const __attribute__((address_space(1))) void*)g,
        (__attribute__((address_space(3))) void*)l, 16, 0, 0);
}

// Wq/Wk/Wv [1024][64] f32 -> Wtt bf16 in MFMA B-fragment order:
// Wtt[((nt*32 + ks)*64 + lane)*8 + e] = W[k = ks*32 + (lane>>4)*8 + e][col],
// col = nt*16 + (lane&15), over concatenated {Q|K|V} 192 cols.
// A wave then loads one B-fragment as ONE contiguous 1KB read.
__global__ __launch_bounds__(256) void prep_weights(
    const float* __restrict__ Wq, const float* __restrict__ Wk,
    const float* __restrict__ Wv, unsigned short* __restrict__ Wtt)
{
    int tw = blockIdx.x * 256 + threadIdx.x;   // 0..24575 (grid 96)
    int nt = tw >> 11;
    int lane = tw & 63;
    int n = nt * 16 + (lane & 15);
    int h = n & 63;
    const float* W = (n < 64) ? Wq : (n < 128) ? Wk : Wv;
    int k0 = ((tw >> 6) & 31) * 32 + (lane >> 4) * 8;
    short8 o;
    #pragma unroll
    for (int e = 0; e < 8; ++e) o[e] = f2bf(W[(k0 + e) * 64 + h]);
    *(short8*)(Wtt + (size_t)tw * 8) = o;
}

// QKV v16 — zero-LDS, zero-barrier direct-load GEMM.
// 512 blocks x 512 thr (8 waves). Wave (wm,wn): rows blk*32+wm*16..+16,
// cols wn*48..+48 (3 nt-tiles, acc = 12 VGPR). 32 k-steps of K=32.
// A: 2 coalesced float4/lane from x (row-major; the one required HBM read).
// B: 3 contiguous 1KB/wave fragment loads from pre-tiled Wtt (L2-resident).
// No LDS in the loop, no barriers, no waitcnt choreography -> compiler
// freely pipelines; 16 waves/CU TLP + unroll-4 ILP hide latency.
__global__ __launch_bounds__(512, 2) void qkv_main(
    const float* __restrict__ x, const unsigned short* __restrict__ Wtt,
    const float* __restrict__ bq, const float* __restrict__ bk,
    const float* __restrict__ bv,
    unsigned short* __restrict__ Q, unsigned short* __restrict__ K,
    unsigned short* __restrict__ Vt)
{
    __shared__ __align__(16) char eq[32 * 272];          // QK epilogue 8.7KB
    __shared__ __align__(16) unsigned short ev[64 * 40]; // V epilogue 5.1KB
    int tid = threadIdx.x;
    int wave = tid >> 6, lane = tid & 63;
    int lo = lane & 15, hi = lane >> 4;
    int wm = wave >> 2, wn = wave & 3;
    int rowbase = blockIdx.x * 32;

    f32x4 acc[3];
    #pragma unroll
    for (int j = 0; j < 3; ++j) acc[j] = (f32x4){0.f, 0.f, 0.f, 0.f};

    const float* xr = x + (size_t)(rowbase + wm * 16 + lo) * E_ + 8 * hi;
    const unsigned short* wp = Wtt + (size_t)(wn * 3) * 32 * 64 * 8 + (size_t)lane * 8;

    #pragma unroll 4
    for (int ks = 0; ks < 32; ++ks) {
        float4 a0 = *(const float4*)(xr + ks * 32);
        float4 a1 = *(const float4*)(xr + ks * 32 + 4);
        short8 af;
        af[0] = f2bf(a0.x); af[1] = f2bf(a0.y);
        af[2] = f2bf(a0.z); af[3] = f2bf(a0.w);
        af[4] = f2bf(a1.x); af[5] = f2bf(a1.y);
        af[6] = f2bf(a1.z); af[7] = f2bf(a1.w);
        #pragma unroll
        for (int j = 0; j < 3; ++j) {
            short8 bf = *(const short8*)(wp + ((size_t)j * 32 + ks) * 64 * 8);
            acc[j] = __builtin_amdgcn_mfma_f32_16x16x32_bf16(af, bf, acc[j], 0, 0, 0);
        }
    }

    // ---- coalesced epilogue: bias -> LDS tiles -> 16B stores ----
    #pragma unroll
    for (int j = 0; j < 3; ++j) {
        int n = wn * 48 + j * 16 + lo;
        #pragma unroll
        for (int r4 = 0; r4 < 4; ++r4) {
            int rr = wm * 16 + 4 * hi + r4;              // local row 0..31
            float v = acc[j][r4];
            if (n < 64) {
                *(unsigned short*)(eq + rr * 272 + n * 2) =
                    (unsigned short)f2bf(v + bq[n]);
            } else if (n < 128) {
                *(unsigned short*)(eq + rr * 272 + n * 2) =
                    (unsigned short)f2bf(v + bk[n - 64]);
            } else {
                ev[(n - 128) * 40 + rr] = (unsigned short)f2bf(v + bv[n - 128]);
            }
        }
    }
    __syncthreads();

    {
        // Q/K: 32 rows x 16 units (Q segs 0-7, K segs 8-15), 1 unit/thread
        int row = tid >> 4, seg = tid & 15;
        short8 val = *(const short8*)(eq + row * 272 + seg * 16);
        if (seg < 8)
            *(short8*)(Q + (size_t)(rowbase + row) * 64 + seg * 8) = val;
        else
            *(short8*)(K + (size_t)(rowbase + row) * 64 + (seg - 8) * 8) = val;
    }
    if (tid < 256) {
        // Vt: 64 h x 4 units (8 s each), 1 unit/thread
        int h = tid >> 2, su = tid & 3;
        int b = rowbase >> 11, sl0 = rowbase & (S_ - 1);
        short8 val = *(const short8*)(ev + h * 40 + su * 8);
        *(short8*)(Vt + ((size_t)(b * 64 + h)) * S_ + sl0 + su * 8) = val;
    }
}

// Flash attention, no-max softmax (unchanged): 3-buffer LDS ring, depth-2
// prefetch, one raw s_barrier per tile with counted vmcnt, masks pre-folded.
__global__ __launch_bounds__(256) void attn_stage(
    const unsigned short* __restrict__ Q, const unsigned short* __restrict__ K,
    const unsigned short* __restrict__ Vt, const int* __restrict__ mask,
    float* __restrict__ part)
{
    __shared__ __align__(16) char kv[3][16384];            // [K 8KB | V 8KB] x3
    __shared__ __align__(16) unsigned short p_lds[4][16][72];
    int tid = threadIdx.x;
    int wave = tid >> 6, lane = tid & 63;
    int lo = lane & 15, hi = lane >> 4;
    int blk = blockIdx.x;
    int c = blk & 3;
    int pr = blk >> 2;
    int b = pr & 7;
    int qt64 = 31 - (pr >> 3);          // heavy first
    int nkt = qt64 + 1;
    int chunk = (nkt + 3) >> 2;
    int kt0 = c * chunk;
    int kt1 = min(kt0 + chunk, nkt);
    int ntile = kt1 - kt0;              // <= 8
    int qrow0 = qt64 * 64 + wave * 16;

    f32x4 o[4];
    float ps[4] = {0.f, 0.f, 0.f, 0.f};
    #pragma unroll
    for (int i = 0; i < 4; ++i) o[i] = (f32x4){0.f, 0.f, 0.f, 0.f};

    #define ASTAGE(bb, kt)                                                        \
        {                                                                         \
            int kbase_ = (kt) * 64;                                               \
            const char* kg = (const char*)K + (size_t)(b * S_ + kbase_) * 128;    \
            const char* vg = (const char*)Vt + (size_t)b * 64 * 4096 + kbase_ * 2;\
            _Pragma("unroll")                                                     \
            for (int j = 0; j < 2; ++j) {                                         \
                int r = (j * 4 + wave) * 8 + (lane >> 3);                         \
                int un = lane & 7;                                                \
                g2l16(kg + r * 128 + ((un ^ (r & 7)) << 4),                       \
                      &kv[bb][(j * 4 + wave) * 1024]);                            \
                g2l16(vg + (size_t)r * 4096 + ((un ^ (r & 7)) << 4),              \
                      &kv[bb][8192 + (j * 4 + wave) * 1024]);                     \
            }                                                                     \
        }

    if (ntile > 0) {
        const unsigned short* qp = Q + ((size_t)(b * S_ + qrow0 + lo)) * 64 + 8 * hi;
        short8 qf0 = *(const short8*)(qp);
        short8 qf1 = *(const short8*)(qp + 32);

        unsigned mbits = 0;
        for (int tt = 0; tt < 8; ++tt) {
            if (tt < ntile) {
                int kbase = (kt0 + tt) * 64;
                #pragma unroll
                for (int nt = 0; nt < 4; ++nt)
                    if (mask[b * S_ + kbase + nt * 16 + lo] != 0)
                        mbits |= (1u << (tt * 4 + nt));
            }
        }
        asm volatile("s_waitcnt vmcnt(0)" ::: "memory");
        __builtin_amdgcn_sched_barrier(0);

        ASTAGE(0, kt0);
        if (ntile > 1) ASTAGE(1, kt0 + 1);
        __builtin_amdgcn_sched_barrier(0);
        if (ntile > 1) asm volatile("s_waitcnt vmcnt(4)" ::: "memory");
        else           asm volatile("s_waitcnt vmcnt(0)" ::: "memory");
        __builtin_amdgcn_sched_barrier(0);
        __builtin_amdgcn_s_barrier();

        for (int t = 0; t < ntile; ++t) {
            int kbase = (kt0 + t) * 64;
            const char* kb = kv[t % 3];
            const char* vb = kv[t % 3] + 8192;

            f32x4 s[4];
            #pragma unroll
            for (int i = 0; i < 4; ++i) s[i] = (f32x4){0.f, 0.f, 0.f, 0.f};
            #pragma unroll
            for (int nt = 0; nt < 4; ++nt) {
                short8 kf0 = *(const short8*)(kb + (nt * 16 + lo) * 128 + ((hi ^ (lo & 7)) << 4));
                short8 kf1 = *(const short8*)(kb + (nt * 16 + lo) * 128 + (((4 + hi) ^ (lo & 7)) << 4));
                s[nt] = __builtin_amdgcn_mfma_f32_16x16x32_bf16(qf0, kf0, s[nt], 0, 0, 0);
                s[nt] = __builtin_amdgcn_mfma_f32_16x16x32_bf16(qf1, kf1, s[nt], 0, 0, 0);
            }

            #pragma unroll
            for (int nt = 0; nt < 4; ++nt) {
                int kpos = kbase + nt * 16 + lo;
                bool mok = (mbits >> (t * 4 + nt)) & 1;
                #pragma unroll
                for (int r = 0; r < 4; ++r) {
                    int qpos = qrow0 + 4 * hi + r;
                    bool ok = mok && (kpos <= qpos);
                    float pv = ok ? __expf(s[nt][r] * 0.125f) : 0.f;
                    ps[r] += pv;
                    p_lds[wave][4 * hi + r][nt * 16 + lo] = (unsigned short)f2bf(pv);
                }
            }

            #pragma unroll
            for (int kk = 0; kk < 2; ++kk) {
                short8 pf = *(const short8*)&p_lds[wave][lo][kk * 32 + 8 * hi];
                #pragma unroll
                for (int nt = 0; nt < 4; ++nt) {
                    short8 vf = *(const short8*)(vb + (nt * 16 + lo) * 128
                                                 + (((kk * 4 + hi) ^ (lo & 7)) << 4));
                    o[nt] = __builtin_amdgcn_mfma_f32_16x16x32_bf16(pf, vf, o[nt], 0, 0, 0);
                }
            }

            if (t + 2 < ntile) ASTAGE((t + 2) % 3, kt0 + t + 2);
            __builtin_amdgcn_sched_barrier(0);
            if (t + 1 < ntile) {
                if (t + 2 < ntile) asm volatile("s_waitcnt vmcnt(4)" ::: "memory");
                else               asm volatile("s_waitcnt vmcnt(0)" ::: "memory");
                __builtin_amdgcn_sched_barrier(0);
                __builtin_amdgcn_s_barrier();
            }
        }
    }
    #undef ASTAGE

    float l[4];
    #pragma unroll
    for (int r = 0; r < 4; ++r) {
        float v = ps[r];
        v += __shfl_xor(v, 1);
        v += __shfl_xor(v, 2);
        v += __shfl_xor(v, 4);
        v += __shfl_xor(v, 8);
        l[r] = v;
    }

    int tile16 = b * 128 + qt64 * 4 + wave;
    float* pp = part + (((size_t)c * 1024 + tile16) * 64 + lane) * 20;
    #pragma unroll
    for (int nt = 0; nt < 4; ++nt) *(f32x4*)(pp + nt * 4) = o[nt];
    f32x4 ll;
    #pragma unroll
    for (int r = 0; r < 4; ++r) ll[r] = l[r];
    *(f32x4*)(pp + 16) = ll;
}

// Sum 4 kv-chunk partials (additive) and normalize.
__global__ __launch_bounds__(256) void attn_comb(
    const float* __restrict__ part, float* __restrict__ out)
{
    int g = blockIdx.x * 256 + threadIdx.x;   // 65536
    int tile = g >> 6, lane = g & 63;
    int lo = lane & 15, hi = lane >> 4;
    int b = tile >> 7, qt = tile & 127;
    int qrow0 = qt * 16;

    f32x4 o[4];
    float l[4] = {0.f, 0.f, 0.f, 0.f};
    #pragma unroll
    for (int i = 0; i < 4; ++i) o[i] = (f32x4){0.f, 0.f, 0.f, 0.f};

    #pragma unroll
    for (int c = 0; c < 4; ++c) {
        const float* pp = part + (((size_t)c * 1024 + tile) * 64 + lane) * 20;
        #pragma unroll
        for (int nt = 0; nt < 4; ++nt) {
            f32x4 po = *(const f32x4*)(pp + nt * 4);
            #pragma unroll
            for (int r = 0; r < 4; ++r) o[nt][r] += po[r];
        }
        f32x4 pl = *(const f32x4*)(pp + 16);
        #pragma unroll
        for (int r = 0; r < 4; ++r) l[r] += pl[r];
    }

    #pragma unroll
    for (int nt = 0; nt < 4; ++nt) {
        #pragma unroll
        for (int r = 0; r < 4; ++r) {
            int qpos = qrow0 + 4 * hi + r;
            out[((size_t)(b * S_ + qpos)) * 64 + nt * 16 + lo] =
                (l[r] > 0.f) ? o[nt][r] / l[r] : 0.f;
        }
    }
}

extern "C" void kernel_launch(void* const* d_in, const int* in_sizes, int n_in,
                              void* d_out, int out_size, void* d_ws, size_t ws_size,
                              hipStream_t stream) {
    const float* x   = (const float*)d_in[0];
    const int*   msk = (const int*)d_in[1];
    const float* Wq  = (const float*)d_in[2];
    const float* bq  = (const float*)d_in[3];
    const float* Wk  = (const float*)d_in[4];
    const float* bk  = (const float*)d_in[5];
    const float* Wv  = (const float*)d_in[6];
    const float* bv  = (const float*)d_in[7];
    float* outp = (float*)d_out;

    // ws layout: Wtt @0 (384KB, pad 512KB) | Q @0x080000 | K @0x280000
    //            Vt @0x480000 | part @0x680000 (4*1024*64*20 f32 = 21 MB)
    char* w = (char*)d_ws;
    unsigned short* Wtt = (unsigned short*)w;
    unsigned short* Qb = (unsigned short*)(w + 0x080000);
    unsigned short* Kb = (unsigned short*)(w + 0x280000);
    unsigned short* Vt = (unsigned short*)(w + 0x480000);
    float* partp = (float*)(w + 0x680000);

    prep_weights<<<dim3(96), dim3(256), 0, stream>>>(Wq, Wk, Wv, Wtt);
    qkv_main<<<dim3(512), dim3(512), 0, stream>>>(x, Wtt, bq, bk, bv, Qb, Kb, Vt);
    attn_stage<<<dim3(1024), dim3(256), 0, stream>>>(Qb, Kb, Vt, msk, partp);
    attn_comb<<<dim3(256), dim3(256), 0, stream>>>(partp, outp);
}